// Round 8
// baseline (99.143 us; speedup 1.0000x reference)
//
#include <hip/hip_runtime.h>
#include <hip/hip_fp16.h>

typedef __attribute__((ext_vector_type(8))) short bf16x8;
typedef __attribute__((ext_vector_type(4))) float f32x4;

__device__ __forceinline__ unsigned short f2bf(float f) {
  unsigned u = __builtin_bit_cast(unsigned, f);
  u += 0x7fffu + ((u >> 16) & 1u);   // round-to-nearest-even
  return (unsigned short)(u >> 16);
}
__device__ __forceinline__ float bf2f(unsigned short s) {
  unsigned u = (unsigned)s << 16;
  return __builtin_bit_cast(float, u);
}
__device__ __forceinline__ unsigned short f2h(float f) {
  __half h = __float2half(f);
  return __builtin_bit_cast(unsigned short, h);
}
__device__ __forceinline__ float h2f(unsigned short bits) {
  __half h = __builtin_bit_cast(__half, bits);
  return __half2float(h);
}

// ---------------------------------------------------------------------------
// Kernel A: prep. blocks 0..511: x NCHW fp32 -> NHWC bf16 xt[b][h][w][c].
// blocks 512..871: repack main_w -> wt[k][128][64], offset_w -> wot[k][32][64].
// ---------------------------------------------------------------------------
__global__ __launch_bounds__(256) void prep_all(
    const float* __restrict__ x, const float* __restrict__ mw,
    const float* __restrict__ ow, unsigned short* __restrict__ xt,
    unsigned short* __restrict__ wt, unsigned short* __restrict__ wot) {
  __shared__ float tile[64 * 129];
  int blk = blockIdx.x;
  int t = threadIdx.x;
  if (blk < 512) {
    const float* xrow = x + ((long)(blk >> 7) << 20) + ((blk & 127) << 7);
#pragma unroll
    for (int i = 0; i < 32; ++i) {
      int idx = t + (i << 8);          // c = idx>>7, w = idx&127
      tile[(idx >> 7) * 129 + (idx & 127)] =
          xrow[((long)(idx >> 7) << 14) + (idx & 127)];
    }
    __syncthreads();
    unsigned short* orow = xt + ((long)blk << 13);
#pragma unroll
    for (int i = 0; i < 32; ++i) {
      int idx = t + (i << 8);          // w = idx>>6, c = idx&63
      orow[idx] = f2bf(tile[(idx & 63) * 129 + (idx >> 6)]);
    }
  } else {
    int idx = (blk - 512) * 256 + t;   // 0..92159
    if (idx < 73728) {
      int c = idx & 63;
      int o = (idx >> 6) & 127;
      int k = idx >> 13;
      wt[idx] = f2bf(mw[o * 576 + c * 9 + k]);
    } else {
      int i2 = idx - 73728;
      int c = i2 & 63;
      int o = (i2 >> 6) & 31;
      int k = i2 >> 11;
      wot[i2] = (o < 18) ? f2bf(ow[o * 576 + c * 9 + k]) : (unsigned short)0;
    }
  }
}

// ---------------------------------------------------------------------------
// Kernel B: offset conv 64->18 via MFMA. Block = 32-px tile, 4 waves;
// wave wv -> (m-frag wv&1, 16-px column wv>>1). Grid 2048 -> 8192 waves
// (100% static occupancy). B-frags straight from xt (L2-hot, clamp+mask).
// No LDS, no barriers.
// ---------------------------------------------------------------------------
__global__ __launch_bounds__(256) void offs_mfma(
    const unsigned short* __restrict__ xt, const unsigned short* __restrict__ wot,
    const float* __restrict__ ob, float* __restrict__ offs) {
  int l = blockIdx.x;
  int bid = ((l & 7) << 8) + (l >> 3);   // XCD swizzle: 256 consecutive bids/XCD
  int b = bid >> 9;
  int r9 = bid & 511;
  int h = r9 >> 2;
  int w0 = (r9 & 3) << 5;
  int t = threadIdx.x;
  int lane = t & 63;
  int wv = t >> 6;
  int mf = wv & 1;
  int pxb = w0 + ((wv >> 1) << 4);
  int l15 = lane & 15;
  int l4 = lane >> 4;
  int l4k = l4 << 3;

  f32x4 oacc = f32x4{0.f, 0.f, 0.f, 0.f};

  const unsigned short* xb = xt + ((long)b << 20);
  const unsigned short* wkb = wot + (((mf << 4) + l15) << 6) + l4k;

#pragma unroll 1
  for (int k = 0; k < 9; ++k) {
    int ky = k / 3, kx = k - 3 * ky;
    int y = h + ky - 1;
    bool yok = (unsigned)y < 128u;
    int yc = min(max(y, 0), 127);
    const unsigned short* xrow = xb + ((long)yc << 13);
    int px = pxb + l15 + kx - 1;
    bool pv = yok && ((unsigned)px < 128u);
    int pxo = min(max(px, 0), 127) << 6;
#pragma unroll
    for (int c0 = 0; c0 < 64; c0 += 32) {
      bf16x8 bv = *(const bf16x8*)(xrow + pxo + c0 + l4k);
      if (!pv) bv = bf16x8{0, 0, 0, 0, 0, 0, 0, 0};
      bf16x8 af = *(const bf16x8*)(wkb + (k << 11) + c0);
      oacc = __builtin_amdgcn_mfma_f32_16x16x32_bf16(af, bv, oacc, 0, 0, 0);
    }
  }

#pragma unroll
  for (int r = 0; r < 4; ++r) {
    int oc = (mf << 4) + (l4 << 2) + r;
    if (oc < 18)
      offs[((long)(b * 18 + oc) << 14) + (h << 7) + pxb + l15] = oacc[r] + ob[oc];
  }
}

// ---------------------------------------------------------------------------
// Kernel C: deformable conv via MFMA, NHWC-bf16 gather.
// Block = 32-px tile x 128 out-ch, 4 waves, grid 2048 (8 blocks/CU, 100%
// static occupancy). Wave wv owns DISJOINT o-quarter (wo=wv*32, 2 m-frags)
// x all 32 px (2 n-frags) -> no wt duplication across waves.
// Double-buffered V tile; sample tap k+1 while MFMA consumes tap k.
// LDS: 4.6K wtab + 2x4.6K vlds = 13.8 KB.
// ---------------------------------------------------------------------------
__global__ __launch_bounds__(256) void deform_mfma(
    const unsigned short* __restrict__ xt, const float* __restrict__ offs,
    const unsigned short* __restrict__ wt, const float* __restrict__ mb,
    float* __restrict__ out) {
  __shared__ uint4 wtab[9][32];
  __shared__ unsigned short vlds[2][32 * 72];

  int l = blockIdx.x;
  int bid = ((l & 7) << 8) + (l >> 3);   // XCD swizzle: 256 consecutive bids/XCD
  int b = bid >> 9;
  int r9 = bid & 511;
  int h = r9 >> 2;
  int w0 = (r9 & 3) << 5;
  int t = threadIdx.x;
  int lane = t & 63;
  int wv = t >> 6;
  int wo = wv << 5;                      // disjoint o-quarter per wave
  int l15 = lane & 15;
  int l4 = lane >> 4;
  int l4k = l4 << 3;

  // ---- sampling table: 288 = 9 taps x 32 px ----
  const float* ob_ = offs + ((long)(b * 18) << 14) + (h << 7) + w0;
  for (int idx = t; idx < 288; idx += 256) {
    int px = idx & 31, k = idx >> 5;
    int ky = k / 3, kx = k - 3 * ky;
    float dy = ob_[((2 * k) << 14) + px];
    float dx = ob_[((2 * k + 1) << 14) + px];
    float py = (float)(h - 1 + ky) + dy;
    float pxf = (float)(w0 + px - 1 + kx) + dx;
    float fy = floorf(py), fx = floorf(pxf);
    float wy = py - fy, wx = pxf - fx;
    int y0 = (int)fy, x0 = (int)fx;
    int y1 = y0 + 1, x1 = x0 + 1;
    bool vy0 = (unsigned)y0 < 128u, vy1 = (unsigned)y1 < 128u;
    bool vx0 = (unsigned)x0 < 128u, vx1 = (unsigned)x1 < 128u;
    float w00 = (vy0 && vx0) ? (1.f - wy) * (1.f - wx) : 0.f;
    float w01 = (vy0 && vx1) ? (1.f - wy) * wx : 0.f;
    float w10 = (vy1 && vx0) ? wy * (1.f - wx) : 0.f;
    float w11 = (vy1 && vx1) ? wy * wx : 0.f;
    int y0c = min(max(y0, 0), 127), y1c = min(max(y1, 0), 127);
    int x0c = min(max(x0, 0), 127), x1c = min(max(x1, 0), 127);
    wtab[k][px] = make_uint4(
        (unsigned)f2h(w00) | ((unsigned)f2h(w01) << 16),
        (unsigned)f2h(w10) | ((unsigned)f2h(w11) << 16),
        (unsigned)(unsigned short)y0c | ((unsigned)(unsigned short)y1c << 16),
        (unsigned)(unsigned short)x0c | ((unsigned)(unsigned short)x1c << 16));
  }

  f32x4 acc[2][2];
#pragma unroll
  for (int m = 0; m < 2; ++m)
#pragma unroll
    for (int n = 0; n < 2; ++n) acc[m][n] = f32x4{0.f, 0.f, 0.f, 0.f};

  const unsigned short* xb = xt + ((long)b << 20);

  // sample tap k into buf: 256 units = 32 px x 8 c-chunks, 1 per thread
  int spx = t >> 3;
  int sco = (t & 7) << 3;
  auto sample = [&](int k, unsigned short* buf) {
    uint4 e = wtab[k][spx];
    float w00 = h2f((unsigned short)(e.x & 0xffff));
    float w01 = h2f((unsigned short)(e.x >> 16));
    float w10 = h2f((unsigned short)(e.y & 0xffff));
    float w11 = h2f((unsigned short)(e.y >> 16));
    int y0 = (int)(short)(e.z & 0xffff), y1 = (int)(short)(e.z >> 16);
    int x0 = (int)(short)(e.w & 0xffff), x1 = (int)(short)(e.w >> 16);
    const unsigned short* r0 = xb + (y0 << 13) + sco;
    const unsigned short* r1 = xb + (y1 << 13) + sco;
    bf16x8 a00 = *(const bf16x8*)(r0 + (x0 << 6));
    bf16x8 a01 = *(const bf16x8*)(r0 + (x1 << 6));
    bf16x8 a10 = *(const bf16x8*)(r1 + (x0 << 6));
    bf16x8 a11 = *(const bf16x8*)(r1 + (x1 << 6));
    unsigned rr[4];
#pragma unroll
    for (int j = 0; j < 4; ++j) {
      float v0 = w00 * bf2f((unsigned short)a00[2 * j]) +
                 w01 * bf2f((unsigned short)a01[2 * j]) +
                 w10 * bf2f((unsigned short)a10[2 * j]) +
                 w11 * bf2f((unsigned short)a11[2 * j]);
      float v1 = w00 * bf2f((unsigned short)a00[2 * j + 1]) +
                 w01 * bf2f((unsigned short)a01[2 * j + 1]) +
                 w10 * bf2f((unsigned short)a10[2 * j + 1]) +
                 w11 * bf2f((unsigned short)a11[2 * j + 1]);
      rr[j] = (unsigned)f2bf(v0) | ((unsigned)f2bf(v1) << 16);
    }
    *(uint4*)&buf[spx * 72 + sco] = make_uint4(rr[0], rr[1], rr[2], rr[3]);
  };

  __syncthreads();          // wtab ready
  sample(0, vlds[0]);
  __syncthreads();          // buf0 ready

  const unsigned short* wkb = wt + ((wo + l15) << 6) + l4k;

#pragma unroll 1
  for (int k = 0; k < 9; ++k) {
    const unsigned short* buf = vlds[k & 1];
    if (k < 8) sample(k + 1, vlds[(k + 1) & 1]);   // overlap with MFMA below

#pragma unroll
    for (int c0 = 0; c0 < 64; c0 += 32) {
      bf16x8 af[2], bfr[2];
#pragma unroll
      for (int m = 0; m < 2; ++m)
        af[m] = *(const bf16x8*)(wkb + (k << 13) + (m << 10) + c0);
#pragma unroll
      for (int n = 0; n < 2; ++n)
        bfr[n] = *(const bf16x8*)&buf[((n << 4) + l15) * 72 + c0 + l4k];
#pragma unroll
      for (int m = 0; m < 2; ++m)
#pragma unroll
        for (int n = 0; n < 2; ++n)
          acc[m][n] = __builtin_amdgcn_mfma_f32_16x16x32_bf16(
              af[m], bfr[n], acc[m][n], 0, 0, 0);
    }
    __syncthreads();        // buffer consumed / next ready
  }

  // ---- epilogue: D row = o (lane>>4)*4+reg, col = px (lane&15) ----
  int hw0 = (h << 7) + w0;
#pragma unroll
  for (int m = 0; m < 2; ++m) {
    int orow = wo + (m << 4) + (l4 << 2);
#pragma unroll
    for (int r = 0; r < 4; ++r) {
      float bias = mb[orow + r];
      long ob2 = ((long)(b * 128 + orow + r) << 14) + hw0;
#pragma unroll
      for (int n = 0; n < 2; ++n)
        out[ob2 + (n << 4) + l15] = acc[m][n][r] + bias;
    }
  }
}

extern "C" void kernel_launch(void* const* d_in, const int* in_sizes, int n_in,
                              void* d_out, int out_size, void* d_ws, size_t ws_size,
                              hipStream_t stream) {
  const float* x  = (const float*)d_in[0];
  const float* ow = (const float*)d_in[1];
  const float* ob = (const float*)d_in[2];
  const float* mw = (const float*)d_in[3];
  const float* mb = (const float*)d_in[4];
  float* out  = (float*)d_out;
  unsigned short* xt  = (unsigned short*)d_ws;                      // 8 MB
  unsigned short* wt  = (unsigned short*)((char*)d_ws + 8388608);   // 144 KB
  unsigned short* wot = (unsigned short*)((char*)d_ws + 8536064);   // 36 KB
  float* offs = (float*)((char*)d_ws + 8572928);                    // 4.5 MB

  prep_all<<<872, 256, 0, stream>>>(x, mw, ow, xt, wt, wot);
  offs_mfma<<<2048, 256, 0, stream>>>(xt, wot, ob, offs);
  deform_mfma<<<2048, 256, 0, stream>>>(xt, offs, wt, mb, out);
}

// Round 9
// 98.977 us; speedup vs baseline: 1.0017x; 1.0017x over previous
//
#include <hip/hip_runtime.h>
#include <hip/hip_fp16.h>

typedef __attribute__((ext_vector_type(8))) _Float16 f16x8;
typedef __attribute__((ext_vector_type(4))) float f32x4;
typedef __attribute__((ext_vector_type(4))) unsigned int u32x4;

__device__ __forceinline__ unsigned short f2h(float f) {
  __half h = __float2half(f);
  return __builtin_bit_cast(unsigned short, h);
}
__device__ __forceinline__ __half2 bc_h2(unsigned u) {
  return __builtin_bit_cast(__half2, u);
}

// ---------------------------------------------------------------------------
// Kernel A: prep. blocks 0..511: x NCHW fp32 -> NHWC fp16 xt[b][h][w][c].
// blocks 512..871: repack main_w -> wt[k][128][64], offset_w -> wot[k][32][64],
// both fp16.
// ---------------------------------------------------------------------------
__global__ __launch_bounds__(256) void prep_all(
    const float* __restrict__ x, const float* __restrict__ mw,
    const float* __restrict__ ow, unsigned short* __restrict__ xt,
    unsigned short* __restrict__ wt, unsigned short* __restrict__ wot) {
  __shared__ float tile[64 * 129];
  int blk = blockIdx.x;
  int t = threadIdx.x;
  if (blk < 512) {
    const float* xrow = x + ((long)(blk >> 7) << 20) + ((blk & 127) << 7);
#pragma unroll
    for (int i = 0; i < 32; ++i) {
      int idx = t + (i << 8);          // c = idx>>7, w = idx&127
      tile[(idx >> 7) * 129 + (idx & 127)] =
          xrow[((long)(idx >> 7) << 14) + (idx & 127)];
    }
    __syncthreads();
    unsigned short* orow = xt + ((long)blk << 13);
#pragma unroll
    for (int i = 0; i < 32; ++i) {
      int idx = t + (i << 8);          // w = idx>>6, c = idx&63
      orow[idx] = f2h(tile[(idx & 63) * 129 + (idx >> 6)]);
    }
  } else {
    int idx = (blk - 512) * 256 + t;   // 0..92159
    if (idx < 73728) {
      int c = idx & 63;
      int o = (idx >> 6) & 127;
      int k = idx >> 13;
      wt[idx] = f2h(mw[o * 576 + c * 9 + k]);
    } else {
      int i2 = idx - 73728;
      int c = i2 & 63;
      int o = (i2 >> 6) & 31;
      int k = i2 >> 11;
      wot[i2] = (o < 18) ? f2h(ow[o * 576 + c * 9 + k]) : (unsigned short)0;
    }
  }
}

// ---------------------------------------------------------------------------
// Kernel B: offset conv 64->18 via f16 MFMA. Block = 32-px tile, 4 waves;
// wave wv -> (m-frag wv&1, 16-px column wv>>1). Grid 2048. No LDS/barriers.
// ---------------------------------------------------------------------------
__global__ __launch_bounds__(256) void offs_mfma(
    const unsigned short* __restrict__ xt, const unsigned short* __restrict__ wot,
    const float* __restrict__ ob, float* __restrict__ offs) {
  int l = blockIdx.x;
  int bid = ((l & 7) << 8) + (l >> 3);   // XCD swizzle
  int b = bid >> 9;
  int r9 = bid & 511;
  int h = r9 >> 2;
  int w0 = (r9 & 3) << 5;
  int t = threadIdx.x;
  int lane = t & 63;
  int wv = t >> 6;
  int mf = wv & 1;
  int pxb = w0 + ((wv >> 1) << 4);
  int l15 = lane & 15;
  int l4 = lane >> 4;
  int l4k = l4 << 3;

  f32x4 oacc = f32x4{0.f, 0.f, 0.f, 0.f};

  const unsigned short* xb = xt + ((long)b << 20);
  const unsigned short* wkb = wot + (((mf << 4) + l15) << 6) + l4k;

#pragma unroll 1
  for (int k = 0; k < 9; ++k) {
    int ky = k / 3, kx = k - 3 * ky;
    int y = h + ky - 1;
    bool yok = (unsigned)y < 128u;
    int yc = min(max(y, 0), 127);
    const unsigned short* xrow = xb + ((long)yc << 13);
    int px = pxb + l15 + kx - 1;
    bool pv = yok && ((unsigned)px < 128u);
    int pxo = min(max(px, 0), 127) << 6;
#pragma unroll
    for (int c0 = 0; c0 < 64; c0 += 32) {
      f16x8 bv = *(const f16x8*)(xrow + pxo + c0 + l4k);
      if (!pv) bv = f16x8{0, 0, 0, 0, 0, 0, 0, 0};
      f16x8 af = *(const f16x8*)(wkb + (k << 11) + c0);
      oacc = __builtin_amdgcn_mfma_f32_16x16x32_f16(af, bv, oacc, 0, 0, 0);
    }
  }

#pragma unroll
  for (int r = 0; r < 4; ++r) {
    int oc = (mf << 4) + (l4 << 2) + r;
    if (oc < 18)
      offs[((long)(b * 18 + oc) << 14) + (h << 7) + pxb + l15] = oacc[r] + ob[oc];
  }
}

// ---------------------------------------------------------------------------
// Kernel C: deformable conv via f16 MFMA, NHWC-fp16 gather.
// Block = 32-px tile x 128 out-ch, 4 waves, grid 2048.
// Phase 1: sampling table wtab (one barrier).
// Phase 2: gather ALL 9 taps -> vlds[9][32][72] fp16 via packed __hfma2
//          bilinear (36 independent loads/thread, deep MLP; one barrier).
// Phase 3: 72 MFMAs, zero barriers; af loads hoistable across whole phase.
// Wave wv owns disjoint o-quarter (wo=wv*32, 2 m-frags) x 32 px (2 n-frags).
// LDS: 4.6K wtab + 41.5K vlds = 46 KB -> 3 blocks/CU.
// ---------------------------------------------------------------------------
__global__ __launch_bounds__(256) void deform_mfma(
    const unsigned short* __restrict__ xt, const float* __restrict__ offs,
    const unsigned short* __restrict__ wt, const float* __restrict__ mb,
    float* __restrict__ out) {
  __shared__ uint4 wtab[9][32];
  __shared__ unsigned short vlds[9][32 * 72];

  int l = blockIdx.x;
  int bid = ((l & 7) << 8) + (l >> 3);   // XCD swizzle
  int b = bid >> 9;
  int r9 = bid & 511;
  int h = r9 >> 2;
  int w0 = (r9 & 3) << 5;
  int t = threadIdx.x;
  int lane = t & 63;
  int wv = t >> 6;
  int wo = wv << 5;                      // disjoint o-quarter per wave
  int l15 = lane & 15;
  int l4 = lane >> 4;
  int l4k = l4 << 3;

  // ---- Phase 1: sampling table (288 = 9 taps x 32 px) ----
  const float* ob_ = offs + ((long)(b * 18) << 14) + (h << 7) + w0;
  for (int idx = t; idx < 288; idx += 256) {
    int px = idx & 31, k = idx >> 5;
    int ky = k / 3, kx = k - 3 * ky;
    float dy = ob_[((2 * k) << 14) + px];
    float dx = ob_[((2 * k + 1) << 14) + px];
    float py = (float)(h - 1 + ky) + dy;
    float pxf = (float)(w0 + px - 1 + kx) + dx;
    float fy = floorf(py), fx = floorf(pxf);
    float wy = py - fy, wx = pxf - fx;
    int y0 = (int)fy, x0 = (int)fx;
    int y1 = y0 + 1, x1 = x0 + 1;
    bool vy0 = (unsigned)y0 < 128u, vy1 = (unsigned)y1 < 128u;
    bool vx0 = (unsigned)x0 < 128u, vx1 = (unsigned)x1 < 128u;
    float w00 = (vy0 && vx0) ? (1.f - wy) * (1.f - wx) : 0.f;
    float w01 = (vy0 && vx1) ? (1.f - wy) * wx : 0.f;
    float w10 = (vy1 && vx0) ? wy * (1.f - wx) : 0.f;
    float w11 = (vy1 && vx1) ? wy * wx : 0.f;
    int y0c = min(max(y0, 0), 127), y1c = min(max(y1, 0), 127);
    int x0c = min(max(x0, 0), 127), x1c = min(max(x1, 0), 127);
    wtab[k][px] = make_uint4(
        (unsigned)f2h(w00) | ((unsigned)f2h(w01) << 16),
        (unsigned)f2h(w10) | ((unsigned)f2h(w11) << 16),
        (unsigned)(unsigned short)y0c | ((unsigned)(unsigned short)y1c << 16),
        (unsigned)(unsigned short)x0c | ((unsigned)(unsigned short)x1c << 16));
  }

  const unsigned short* xb = xt + ((long)b << 20);
  __syncthreads();          // wtab ready

  // ---- Phase 2: gather all 9 taps; 1 (px, c-chunk) unit per thread ----
  int spx = t >> 3;
  int sco = (t & 7) << 3;
#pragma unroll 3
  for (int k = 0; k < 9; ++k) {
    uint4 e = wtab[k][spx];
    __half2 w00 = bc_h2((e.x & 0xffffu) | (e.x << 16));
    __half2 w01 = bc_h2((e.x >> 16) | (e.x & 0xffff0000u));
    __half2 w10 = bc_h2((e.y & 0xffffu) | (e.y << 16));
    __half2 w11 = bc_h2((e.y >> 16) | (e.y & 0xffff0000u));
    int y0 = (int)(short)(e.z & 0xffff), y1 = (int)(short)(e.z >> 16);
    int x0 = (int)(short)(e.w & 0xffff), x1 = (int)(short)(e.w >> 16);
    const unsigned short* r0 = xb + (y0 << 13) + sco;
    const unsigned short* r1 = xb + (y1 << 13) + sco;
    u32x4 a00 = *(const u32x4*)(r0 + (x0 << 6));
    u32x4 a01 = *(const u32x4*)(r0 + (x1 << 6));
    u32x4 a10 = *(const u32x4*)(r1 + (x0 << 6));
    u32x4 a11 = *(const u32x4*)(r1 + (x1 << 6));
    u32x4 rr;
#pragma unroll
    for (int j = 0; j < 4; ++j) {
      __half2 v = __hmul2(w00, bc_h2(a00[j]));
      v = __hfma2(w01, bc_h2(a01[j]), v);
      v = __hfma2(w10, bc_h2(a10[j]), v);
      v = __hfma2(w11, bc_h2(a11[j]), v);
      rr[j] = __builtin_bit_cast(unsigned, v);
    }
    *(u32x4*)&vlds[k][spx * 72 + sco] = rr;
  }
  __syncthreads();          // whole V ready

  // ---- Phase 3: MFMA, no barriers ----
  f32x4 acc[2][2];
#pragma unroll
  for (int m = 0; m < 2; ++m)
#pragma unroll
    for (int n = 0; n < 2; ++n) acc[m][n] = f32x4{0.f, 0.f, 0.f, 0.f};

  const unsigned short* wkb = wt + ((wo + l15) << 6) + l4k;

#pragma unroll 3
  for (int k = 0; k < 9; ++k) {
#pragma unroll
    for (int c0 = 0; c0 < 64; c0 += 32) {
      f16x8 af[2], bfr[2];
#pragma unroll
      for (int m = 0; m < 2; ++m)
        af[m] = *(const f16x8*)(wkb + (k << 13) + (m << 10) + c0);
#pragma unroll
      for (int n = 0; n < 2; ++n)
        bfr[n] = *(const f16x8*)&vlds[k][((n << 4) + l15) * 72 + c0 + l4k];
#pragma unroll
      for (int m = 0; m < 2; ++m)
#pragma unroll
        for (int n = 0; n < 2; ++n)
          acc[m][n] = __builtin_amdgcn_mfma_f32_16x16x32_f16(
              af[m], bfr[n], acc[m][n], 0, 0, 0);
    }
  }

  // ---- epilogue: D row = o (lane>>4)*4+reg, col = px (lane&15) ----
  int hw0 = (h << 7) + w0;
#pragma unroll
  for (int m = 0; m < 2; ++m) {
    int orow = wo + (m << 4) + (l4 << 2);
#pragma unroll
    for (int r = 0; r < 4; ++r) {
      float bias = mb[orow + r];
      long ob2 = ((long)(b * 128 + orow + r) << 14) + hw0;
#pragma unroll
      for (int n = 0; n < 2; ++n)
        out[ob2 + (n << 4) + l15] = acc[m][n][r] + bias;
    }
  }
}

extern "C" void kernel_launch(void* const* d_in, const int* in_sizes, int n_in,
                              void* d_out, int out_size, void* d_ws, size_t ws_size,
                              hipStream_t stream) {
  const float* x  = (const float*)d_in[0];
  const float* ow = (const float*)d_in[1];
  const float* ob = (const float*)d_in[2];
  const float* mw = (const float*)d_in[3];
  const float* mb = (const float*)d_in[4];
  float* out  = (float*)d_out;
  unsigned short* xt  = (unsigned short*)d_ws;                      // 8 MB
  unsigned short* wt  = (unsigned short*)((char*)d_ws + 8388608);   // 144 KB
  unsigned short* wot = (unsigned short*)((char*)d_ws + 8536064);   // 36 KB
  float* offs = (float*)((char*)d_ws + 8572928);                    // 4.5 MB

  prep_all<<<872, 256, 0, stream>>>(x, mw, ow, xt, wt, wot);
  offs_mfma<<<2048, 256, 0, stream>>>(xt, wot, ob, offs);
  deform_mfma<<<2048, 256, 0, stream>>>(xt, offs, wt, mb, out);
}